// Round 1
// baseline (1562.349 us; speedup 1.0000x reference)
//
#include <hip/hip_runtime.h>

#define N_NODES 100000
#define N_EDGES 1600000
#define D 128

// ---------------------------------------------------------------------------
// Kernel 1: edge scatter — agg[dst] += w_e * x[src], one wave per edge.
// Aggregates RAW x (transform commutes with aggregation): A(XW^T) = (AX)W^T.
// Each lane handles 2 consecutive floats (float2 = coalesced 512B per wave).
// unsafeAtomicAdd -> global_atomic_add_f32 (no CAS loop, no return).
// ---------------------------------------------------------------------------
__global__ __launch_bounds__(256) void gcn_scatter(
    const float* __restrict__ x,
    const int* __restrict__ ei,     // [2, E] flat: [0..E) = src, [E..2E) = dst
    const float* __restrict__ ew,   // [E]
    float* __restrict__ agg)        // [N, D], pre-zeroed
{
    const int lane = threadIdx.x & 63;
    const int wave = (blockIdx.x * blockDim.x + threadIdx.x) >> 6;
    const int nwaves = (gridDim.x * blockDim.x) >> 6;

    for (int e = wave; e < N_EDGES; e += nwaves) {
        const int src = ei[e];
        const int dst = ei[N_EDGES + e];
        const float w = ew[e];
        const float2 v = ((const float2*)(x + (size_t)src * D))[lane];
        float* op = agg + (size_t)dst * D + lane * 2;
        unsafeAtomicAdd(op,     w * v.x);
        unsafeAtomicAdd(op + 1, w * v.y);
    }
}

// ---------------------------------------------------------------------------
// Kernel 2: fused transform: out = relu(prelu(agg @ W^T + bias, a))
// In-place safe (A may alias out): each block stages its 32-row tile into LDS
// before writing, and blocks only write their own rows.
// LDS: Wt[128][128] transposed (64KB) + xs[32][128] (16KB) = 80KB -> 2 blk/CU.
// Thread (tm,tn): tm=tid>>5 covers rows tm*4..tm*4+3, tn=tid&31 covers cols
// 4*tn..4*tn+3 -> 4x4 register tile, float4 LDS reads (conflict-free).
// ---------------------------------------------------------------------------
#define MT 32

__global__ __launch_bounds__(256, 2) void gcn_transform(
    const float* __restrict__ A,    // [N, D] aggregated (may alias out)
    const float* __restrict__ W,    // [D_out, D_in] row-major
    const float* __restrict__ bias, // [D]
    const float* __restrict__ pa,   // [1]
    float* __restrict__ out)        // [N, D]
{
    __shared__ float Wt[D][D];      // Wt[k][n] = W[n][k]
    __shared__ float xs[MT][D];

    const int tid = threadIdx.x;
    const int row0 = blockIdx.x * MT;

    // Stage W transposed: coalesced float4 global reads, scalar LDS writes.
    // 4096 float4s / 256 threads = 16 each. (One-time; write conflicts minor.)
    for (int i = tid; i < D * (D / 4); i += 256) {
        const float4 v = ((const float4*)W)[i];
        const int n = i >> 5;            // W row
        const int k4 = (i & 31) << 2;    // starting k
        Wt[k4 + 0][n] = v.x;
        Wt[k4 + 1][n] = v.y;
        Wt[k4 + 2][n] = v.z;
        Wt[k4 + 3][n] = v.w;
    }

    // Stage A tile: 32 rows x 128 = 1024 float4s, coalesced.
    for (int i = tid; i < MT * (D / 4); i += 256) {
        const int r = i >> 5;
        const int c4 = i & 31;
        ((float4*)xs[r])[c4] = ((const float4*)(A + (size_t)(row0 + r) * D))[c4];
    }
    __syncthreads();

    const int tn = tid & 31;   // col group: cols 4*tn..4*tn+3
    const int tm = tid >> 5;   // row group: rows tm*4..tm*4+3

    float acc[4][4] = {};

    #pragma unroll
    for (int k = 0; k < D; k += 4) {
        const float4 wv0 = *(const float4*)&Wt[k + 0][tn * 4];
        const float4 wv1 = *(const float4*)&Wt[k + 1][tn * 4];
        const float4 wv2 = *(const float4*)&Wt[k + 2][tn * 4];
        const float4 wv3 = *(const float4*)&Wt[k + 3][tn * 4];
        #pragma unroll
        for (int i = 0; i < 4; ++i) {
            const float4 xv = *(const float4*)&xs[tm * 4 + i][k];
            acc[i][0] += xv.x * wv0.x + xv.y * wv1.x + xv.z * wv2.x + xv.w * wv3.x;
            acc[i][1] += xv.x * wv0.y + xv.y * wv1.y + xv.z * wv2.y + xv.w * wv3.y;
            acc[i][2] += xv.x * wv0.z + xv.y * wv1.z + xv.z * wv2.z + xv.w * wv3.z;
            acc[i][3] += xv.x * wv0.w + xv.y * wv1.w + xv.z * wv2.w + xv.w * wv3.w;
        }
    }

    // Epilogue: bias + prelu + relu, float4 coalesced store (in place).
    const float a = pa[0];
    const float4 bv = ((const float4*)bias)[tn];

    #pragma unroll
    for (int i = 0; i < 4; ++i) {
        const int gr = row0 + tm * 4 + i;
        float t0 = acc[i][0] + bv.x;
        float t1 = acc[i][1] + bv.y;
        float t2 = acc[i][2] + bv.z;
        float t3 = acc[i][3] + bv.w;
        float4 r;
        r.x = fmaxf(t0 >= 0.f ? t0 : a * t0, 0.f);
        r.y = fmaxf(t1 >= 0.f ? t1 : a * t1, 0.f);
        r.z = fmaxf(t2 >= 0.f ? t2 : a * t2, 0.f);
        r.w = fmaxf(t3 >= 0.f ? t3 : a * t3, 0.f);
        ((float4*)(out + (size_t)gr * D))[tn] = r;
    }
}

// ---------------------------------------------------------------------------
extern "C" void kernel_launch(void* const* d_in, const int* in_sizes, int n_in,
                              void* d_out, int out_size, void* d_ws, size_t ws_size,
                              hipStream_t stream) {
    const float* x    = (const float*)d_in[0];
    const int*   ei   = (const int*)d_in[1];
    const float* ew   = (const float*)d_in[2];
    const float* W    = (const float*)d_in[3];
    const float* bias = (const float*)d_in[4];
    const float* pa   = (const float*)d_in[5];
    float* out = (float*)d_out;

    // Zero the aggregation buffer (d_out is poisoned 0xAA before every call).
    hipMemsetAsync(out, 0, (size_t)N_NODES * D * sizeof(float), stream);

    // Edge scatter-aggregate: 12800 blocks * 4 waves = 51200 waves,
    // ~31 edges each (grid-stride).
    gcn_scatter<<<12800, 256, 0, stream>>>(x, ei, ew, out);

    // Fused in-place transform + activation: 100000 / 32 = 3125 blocks.
    gcn_transform<<<N_NODES / MT, 256, 0, stream>>>(out, W, bias, pa, out);
}

// Round 2
// 560.104 us; speedup vs baseline: 2.7894x; 2.7894x over previous
//
#include <hip/hip_runtime.h>

#define N_NODES 100000
#define N_EDGES 1600000
#define D 128
#define NB ((N_NODES + 1023) / 1024)   // scan chunks of 1024 -> 98

// ---------------------------------------------------------------------------
// CSR build path (no float atomics):
//   deg -> exclusive scan -> off/cursor -> fill (src,w) -> per-node gather
// ---------------------------------------------------------------------------

__global__ __launch_bounds__(256) void k_hist(
    const int* __restrict__ ei, int* __restrict__ deg)
{
    int i = blockIdx.x * blockDim.x + threadIdx.x;
    if (i < N_EDGES) atomicAdd(&deg[ei[N_EDGES + i]], 1);
}

// Block-level scan: each block handles 1024 elements (256 thr x 4).
__global__ __launch_bounds__(256) void k_scan_a(
    const int* __restrict__ deg, int* __restrict__ off, int* __restrict__ bsum)
{
    __shared__ int sh[256];
    const int t = threadIdx.x;
    const int base = blockIdx.x * 1024 + t * 4;
    int a0 = (base + 0 < N_NODES) ? deg[base + 0] : 0;
    int a1 = (base + 1 < N_NODES) ? deg[base + 1] : 0;
    int a2 = (base + 2 < N_NODES) ? deg[base + 2] : 0;
    int a3 = (base + 3 < N_NODES) ? deg[base + 3] : 0;
    const int T = a0 + a1 + a2 + a3;
    sh[t] = T;
    __syncthreads();
    for (int d = 1; d < 256; d <<= 1) {
        int v = (t >= d) ? sh[t - d] : 0;
        __syncthreads();
        sh[t] += v;
        __syncthreads();
    }
    const int excl = sh[t] - T;
    if (base + 0 < N_NODES) off[base + 0] = excl;
    if (base + 1 < N_NODES) off[base + 1] = excl + a0;
    if (base + 2 < N_NODES) off[base + 2] = excl + a0 + a1;
    if (base + 3 < N_NODES) off[base + 3] = excl + a0 + a1 + a2;
    if (t == 255) bsum[blockIdx.x] = sh[255];
}

// Single block scans the 98 block sums -> boff[0..NB] (boff[NB] = total).
__global__ __launch_bounds__(128) void k_scan_b(
    const int* __restrict__ bsum, int* __restrict__ boff)
{
    __shared__ int sh[128];
    const int t = threadIdx.x;
    const int v = (t < NB) ? bsum[t] : 0;
    sh[t] = v;
    __syncthreads();
    for (int d = 1; d < 128; d <<= 1) {
        int u = (t >= d) ? sh[t - d] : 0;
        __syncthreads();
        sh[t] += u;
        __syncthreads();
    }
    if (t < NB) boff[t] = sh[t] - v;
    if (t == 127) boff[NB] = sh[127];
}

__global__ __launch_bounds__(256) void k_scan_c(
    int* __restrict__ off, int* __restrict__ cursor, const int* __restrict__ boff)
{
    int i = blockIdx.x * blockDim.x + threadIdx.x;
    if (i < N_NODES) {
        int v = off[i] + boff[i >> 10];
        off[i] = v;
        cursor[i] = v;
    } else if (i == N_NODES) {
        off[N_NODES] = boff[NB];
    }
}

__global__ __launch_bounds__(256) void k_fill(
    const int* __restrict__ ei, const float* __restrict__ ew,
    int* __restrict__ cursor, int* __restrict__ csr_src, float* __restrict__ csr_w)
{
    int e = blockIdx.x * blockDim.x + threadIdx.x;
    if (e < N_EDGES) {
        int dst = ei[N_EDGES + e];
        int pos = atomicAdd(&cursor[dst], 1);
        csr_src[pos] = ei[e];
        csr_w[pos] = ew[e];
    }
}

// One wave per node: lanes hold 2 consecutive floats of the D=128 row.
// 4-deep manual unroll for load-latency ILP (edges are L2/L3-resident).
__global__ __launch_bounds__(256) void k_gather(
    const float* __restrict__ x, const int* __restrict__ off,
    const int* __restrict__ csr_src, const float* __restrict__ csr_w,
    float* __restrict__ agg)
{
    const int lane = threadIdx.x & 63;
    const int n = (blockIdx.x * blockDim.x + threadIdx.x) >> 6;
    if (n >= N_NODES) return;

    const int beg = off[n];
    const int end = off[n + 1];
    const float2* __restrict__ x2 = (const float2*)x;

    float2 acc = make_float2(0.f, 0.f);
    int e = beg;
    for (; e + 4 <= end; e += 4) {
        const int   s0 = csr_src[e + 0], s1 = csr_src[e + 1];
        const int   s2 = csr_src[e + 2], s3 = csr_src[e + 3];
        const float w0 = csr_w[e + 0], w1 = csr_w[e + 1];
        const float w2 = csr_w[e + 2], w3 = csr_w[e + 3];
        const float2 v0 = x2[(size_t)s0 * 64 + lane];
        const float2 v1 = x2[(size_t)s1 * 64 + lane];
        const float2 v2 = x2[(size_t)s2 * 64 + lane];
        const float2 v3 = x2[(size_t)s3 * 64 + lane];
        acc.x += w0 * v0.x + w1 * v1.x + w2 * v2.x + w3 * v3.x;
        acc.y += w0 * v0.y + w1 * v1.y + w2 * v2.y + w3 * v3.y;
    }
    for (; e < end; ++e) {
        const int s = csr_src[e];
        const float w = csr_w[e];
        const float2 v = x2[(size_t)s * 64 + lane];
        acc.x += w * v.x;
        acc.y += w * v.y;
    }
    ((float2*)agg)[(size_t)n * 64 + lane] = acc;
}

// ---------------------------------------------------------------------------
// Fallback scatter (only used if ws_size < CSR需要) — proven correct in R1.
// ---------------------------------------------------------------------------
__global__ __launch_bounds__(256) void gcn_scatter(
    const float* __restrict__ x, const int* __restrict__ ei,
    const float* __restrict__ ew, float* __restrict__ agg)
{
    const int lane = threadIdx.x & 63;
    const int wave = (blockIdx.x * blockDim.x + threadIdx.x) >> 6;
    const int nwaves = (gridDim.x * blockDim.x) >> 6;
    for (int e = wave; e < N_EDGES; e += nwaves) {
        const int src = ei[e];
        const int dst = ei[N_EDGES + e];
        const float w = ew[e];
        const float2 v = ((const float2*)(x + (size_t)src * D))[lane];
        float* op = agg + (size_t)dst * D + lane * 2;
        unsafeAtomicAdd(op,     w * v.x);
        unsafeAtomicAdd(op + 1, w * v.y);
    }
}

// ---------------------------------------------------------------------------
// Fused transform: out = relu(prelu(agg @ W^T + bias, a)) — in place.
// ---------------------------------------------------------------------------
#define MT 32

__global__ __launch_bounds__(256, 2) void gcn_transform(
    const float* __restrict__ A, const float* __restrict__ W,
    const float* __restrict__ bias, const float* __restrict__ pa,
    float* __restrict__ out)
{
    __shared__ float Wt[D][D];
    __shared__ float xs[MT][D];

    const int tid = threadIdx.x;
    const int row0 = blockIdx.x * MT;

    for (int i = tid; i < D * (D / 4); i += 256) {
        const float4 v = ((const float4*)W)[i];
        const int n = i >> 5;
        const int k4 = (i & 31) << 2;
        Wt[k4 + 0][n] = v.x;
        Wt[k4 + 1][n] = v.y;
        Wt[k4 + 2][n] = v.z;
        Wt[k4 + 3][n] = v.w;
    }
    for (int i = tid; i < MT * (D / 4); i += 256) {
        const int r = i >> 5;
        const int c4 = i & 31;
        ((float4*)xs[r])[c4] = ((const float4*)(A + (size_t)(row0 + r) * D))[c4];
    }
    __syncthreads();

    const int tn = tid & 31;
    const int tm = tid >> 5;
    float acc[4][4] = {};

    #pragma unroll
    for (int k = 0; k < D; k += 4) {
        const float4 wv0 = *(const float4*)&Wt[k + 0][tn * 4];
        const float4 wv1 = *(const float4*)&Wt[k + 1][tn * 4];
        const float4 wv2 = *(const float4*)&Wt[k + 2][tn * 4];
        const float4 wv3 = *(const float4*)&Wt[k + 3][tn * 4];
        #pragma unroll
        for (int i = 0; i < 4; ++i) {
            const float4 xv = *(const float4*)&xs[tm * 4 + i][k];
            acc[i][0] += xv.x * wv0.x + xv.y * wv1.x + xv.z * wv2.x + xv.w * wv3.x;
            acc[i][1] += xv.x * wv0.y + xv.y * wv1.y + xv.z * wv2.y + xv.w * wv3.y;
            acc[i][2] += xv.x * wv0.z + xv.y * wv1.z + xv.z * wv2.z + xv.w * wv3.z;
            acc[i][3] += xv.x * wv0.w + xv.y * wv1.w + xv.z * wv2.w + xv.w * wv3.w;
        }
    }

    const float a = pa[0];
    const float4 bv = ((const float4*)bias)[tn];

    #pragma unroll
    for (int i = 0; i < 4; ++i) {
        const int gr = row0 + tm * 4 + i;
        float t0 = acc[i][0] + bv.x;
        float t1 = acc[i][1] + bv.y;
        float t2 = acc[i][2] + bv.z;
        float t3 = acc[i][3] + bv.w;
        float4 r;
        r.x = fmaxf(t0 >= 0.f ? t0 : a * t0, 0.f);
        r.y = fmaxf(t1 >= 0.f ? t1 : a * t1, 0.f);
        r.z = fmaxf(t2 >= 0.f ? t2 : a * t2, 0.f);
        r.w = fmaxf(t3 >= 0.f ? t3 : a * t3, 0.f);
        ((float4*)(out + (size_t)gr * D))[tn] = r;
    }
}

// ---------------------------------------------------------------------------
extern "C" void kernel_launch(void* const* d_in, const int* in_sizes, int n_in,
                              void* d_out, int out_size, void* d_ws, size_t ws_size,
                              hipStream_t stream) {
    const float* x    = (const float*)d_in[0];
    const int*   ei   = (const int*)d_in[1];
    const float* ew   = (const float*)d_in[2];
    const float* W    = (const float*)d_in[3];
    const float* bias = (const float*)d_in[4];
    const float* pa   = (const float*)d_in[5];
    float* out = (float*)d_out;

    // Workspace layout (ints unless noted)
    int* deg     = (int*)d_ws;               // N
    int* off     = deg + N_NODES;            // N+1
    int* cursor  = off + N_NODES + 1;        // N
    int* bsum    = cursor + N_NODES;         // NB
    int* boff    = bsum + NB;                // NB+1
    int* csr_src = boff + NB + 1;            // E
    float* csr_w = (float*)(csr_src + N_EDGES); // E
    const size_t need = (size_t)(3 * N_NODES + 2 + 2 * NB + 2 * N_EDGES + 8) * 4;

    if (ws_size >= need) {
        hipMemsetAsync(deg, 0, (size_t)N_NODES * sizeof(int), stream);
        k_hist  <<<(N_EDGES + 255) / 256, 256, 0, stream>>>(ei, deg);
        k_scan_a<<<NB, 256, 0, stream>>>(deg, off, bsum);
        k_scan_b<<<1, 128, 0, stream>>>(bsum, boff);
        k_scan_c<<<(N_NODES + 256) / 256, 256, 0, stream>>>(off, cursor, boff);
        k_fill  <<<(N_EDGES + 255) / 256, 256, 0, stream>>>(ei, ew, cursor, csr_src, csr_w);
        k_gather<<<(N_NODES + 3) / 4, 256, 0, stream>>>(x, off, csr_src, csr_w, out);
    } else {
        hipMemsetAsync(out, 0, (size_t)N_NODES * D * sizeof(float), stream);
        gcn_scatter<<<12800, 256, 0, stream>>>(x, ei, ew, out);
    }

    gcn_transform<<<N_NODES / MT, 256, 0, stream>>>(out, W, bias, pa, out);
}

// Round 3
// 485.618 us; speedup vs baseline: 3.2172x; 1.1534x over previous
//
#include <hip/hip_runtime.h>

#define N_NODES 100000
#define N_EDGES 1600000
#define D 128
#define NB ((N_NODES + 1023) / 1024)   // scan chunks of 1024 -> 98

// ---------------------------------------------------------------------------
// CSR build path (no float atomics):
//   deg -> exclusive scan -> off/cursor -> fill {src,w} pairs -> gather
// ---------------------------------------------------------------------------

__global__ __launch_bounds__(256) void k_hist(
    const int* __restrict__ ei, int* __restrict__ deg)
{
    int i = blockIdx.x * blockDim.x + threadIdx.x;
    if (i < N_EDGES) atomicAdd(&deg[ei[N_EDGES + i]], 1);
}

// Block-level scan: each block handles 1024 elements (256 thr x 4).
__global__ __launch_bounds__(256) void k_scan_a(
    const int* __restrict__ deg, int* __restrict__ off, int* __restrict__ bsum)
{
    __shared__ int sh[256];
    const int t = threadIdx.x;
    const int base = blockIdx.x * 1024 + t * 4;
    int a0 = (base + 0 < N_NODES) ? deg[base + 0] : 0;
    int a1 = (base + 1 < N_NODES) ? deg[base + 1] : 0;
    int a2 = (base + 2 < N_NODES) ? deg[base + 2] : 0;
    int a3 = (base + 3 < N_NODES) ? deg[base + 3] : 0;
    const int T = a0 + a1 + a2 + a3;
    sh[t] = T;
    __syncthreads();
    for (int d = 1; d < 256; d <<= 1) {
        int v = (t >= d) ? sh[t - d] : 0;
        __syncthreads();
        sh[t] += v;
        __syncthreads();
    }
    const int excl = sh[t] - T;
    if (base + 0 < N_NODES) off[base + 0] = excl;
    if (base + 1 < N_NODES) off[base + 1] = excl + a0;
    if (base + 2 < N_NODES) off[base + 2] = excl + a0 + a1;
    if (base + 3 < N_NODES) off[base + 3] = excl + a0 + a1 + a2;
    if (t == 255) bsum[blockIdx.x] = sh[255];
}

__global__ __launch_bounds__(128) void k_scan_b(
    const int* __restrict__ bsum, int* __restrict__ boff)
{
    __shared__ int sh[128];
    const int t = threadIdx.x;
    const int v = (t < NB) ? bsum[t] : 0;
    sh[t] = v;
    __syncthreads();
    for (int d = 1; d < 128; d <<= 1) {
        int u = (t >= d) ? sh[t - d] : 0;
        __syncthreads();
        sh[t] += u;
        __syncthreads();
    }
    if (t < NB) boff[t] = sh[t] - v;
    if (t == 127) boff[NB] = sh[127];
}

__global__ __launch_bounds__(256) void k_scan_c(
    int* __restrict__ off, int* __restrict__ cursor, const int* __restrict__ boff)
{
    int i = blockIdx.x * blockDim.x + threadIdx.x;
    if (i < N_NODES) {
        int v = off[i] + boff[i >> 10];
        off[i] = v;
        cursor[i] = v;
    } else if (i == N_NODES) {
        off[N_NODES] = boff[NB];
    }
}

// Fill CSR as interleaved {src, w_bits} pairs: one 8B scattered write.
__global__ __launch_bounds__(256) void k_fill(
    const int* __restrict__ ei, const float* __restrict__ ew,
    int* __restrict__ cursor, int2* __restrict__ csr_pair)
{
    int e = blockIdx.x * blockDim.x + threadIdx.x;
    if (e < N_EDGES) {
        int dst = ei[N_EDGES + e];
        int pos = atomicAdd(&cursor[dst], 1);
        csr_pair[pos] = make_int2(ei[e], __float_as_int(ew[e]));
    }
}

// One wave per node: lanes hold 2 consecutive floats of the D=128 row.
// 4-deep unroll for load-latency ILP (x is L2/L3-resident).
__global__ __launch_bounds__(256) void k_gather(
    const float* __restrict__ x, const int* __restrict__ off,
    const int2* __restrict__ csr_pair, float* __restrict__ agg)
{
    const int lane = threadIdx.x & 63;
    const int n = (blockIdx.x * blockDim.x + threadIdx.x) >> 6;
    if (n >= N_NODES) return;

    const int beg = off[n];
    const int end = off[n + 1];
    const float2* __restrict__ x2 = (const float2*)x;

    float2 acc = make_float2(0.f, 0.f);
    int e = beg;
    for (; e + 4 <= end; e += 4) {
        const int2 p0 = csr_pair[e + 0], p1 = csr_pair[e + 1];
        const int2 p2 = csr_pair[e + 2], p3 = csr_pair[e + 3];
        const float2 v0 = x2[(size_t)p0.x * 64 + lane];
        const float2 v1 = x2[(size_t)p1.x * 64 + lane];
        const float2 v2 = x2[(size_t)p2.x * 64 + lane];
        const float2 v3 = x2[(size_t)p3.x * 64 + lane];
        const float w0 = __int_as_float(p0.y), w1 = __int_as_float(p1.y);
        const float w2 = __int_as_float(p2.y), w3 = __int_as_float(p3.y);
        acc.x += w0 * v0.x + w1 * v1.x + w2 * v2.x + w3 * v3.x;
        acc.y += w0 * v0.y + w1 * v1.y + w2 * v2.y + w3 * v3.y;
    }
    for (; e < end; ++e) {
        const int2 p = csr_pair[e];
        const float w = __int_as_float(p.y);
        const float2 v = x2[(size_t)p.x * 64 + lane];
        acc.x += w * v.x;
        acc.y += w * v.y;
    }
    ((float2*)agg)[(size_t)n * 64 + lane] = acc;
}

// ---------------------------------------------------------------------------
// Fallback scatter (only if ws too small) — proven correct in R1.
// ---------------------------------------------------------------------------
__global__ __launch_bounds__(256) void gcn_scatter(
    const float* __restrict__ x, const int* __restrict__ ei,
    const float* __restrict__ ew, float* __restrict__ agg)
{
    const int lane = threadIdx.x & 63;
    const int wave = (blockIdx.x * blockDim.x + threadIdx.x) >> 6;
    const int nwaves = (gridDim.x * blockDim.x) >> 6;
    for (int e = wave; e < N_EDGES; e += nwaves) {
        const int src = ei[e];
        const int dst = ei[N_EDGES + e];
        const float w = ew[e];
        const float2 v = ((const float2*)(x + (size_t)src * D))[lane];
        float* op = agg + (size_t)dst * D + lane * 2;
        unsafeAtomicAdd(op,     w * v.x);
        unsafeAtomicAdd(op + 1, w * v.y);
    }
}

// ---------------------------------------------------------------------------
// Fused transform: out = relu(prelu(agg @ W^T + bias, a)) — in place.
// Staging remap: lane-consecutive n -> LDS write banks 0..31, conflict-free
// (old mapping had 32 lanes sharing n -> 32-way conflict, 5e7 cycles).
// ---------------------------------------------------------------------------
#define MT 32

__global__ __launch_bounds__(256, 2) void gcn_transform(
    const float* __restrict__ A, const float* __restrict__ W,
    const float* __restrict__ bias, const float* __restrict__ pa,
    float* __restrict__ out)
{
    __shared__ float Wt[D][D];      // Wt[k][n] = W[n][k]
    __shared__ float xs[MT][D];

    const int tid = threadIdx.x;
    const int row0 = blockIdx.x * MT;

    // Stage W transposed. j -> (n = j&127, kg = j>>7). Lane-consecutive n:
    // LDS write bank = n%32 -> banks 0..31 across a lane group, conflict-free.
    // Global reads are 512B-strided but W (64KB) is L2-resident.
    for (int j = tid; j < D * (D / 4); j += 256) {
        const int n = j & 127;
        const int kg = j >> 7;
        const float4 v = ((const float4*)W)[n * (D / 4) + kg];
        const int k4 = kg << 2;
        Wt[k4 + 0][n] = v.x;
        Wt[k4 + 1][n] = v.y;
        Wt[k4 + 2][n] = v.z;
        Wt[k4 + 3][n] = v.w;
    }

    // Stage A tile: 32 rows x 128 = 1024 float4s, coalesced, conflict-free.
    for (int i = tid; i < MT * (D / 4); i += 256) {
        const int r = i >> 5;
        const int c4 = i & 31;
        ((float4*)xs[r])[c4] = ((const float4*)(A + (size_t)(row0 + r) * D))[c4];
    }
    __syncthreads();

    const int tn = tid & 31;   // cols 4*tn..4*tn+3
    const int tm = tid >> 5;   // rows tm*4..tm*4+3
    float acc[4][4] = {};

    #pragma unroll
    for (int k = 0; k < D; k += 4) {
        const float4 wv0 = *(const float4*)&Wt[k + 0][tn * 4];
        const float4 wv1 = *(const float4*)&Wt[k + 1][tn * 4];
        const float4 wv2 = *(const float4*)&Wt[k + 2][tn * 4];
        const float4 wv3 = *(const float4*)&Wt[k + 3][tn * 4];
        #pragma unroll
        for (int i = 0; i < 4; ++i) {
            const float4 xv = *(const float4*)&xs[tm * 4 + i][k];
            acc[i][0] += xv.x * wv0.x + xv.y * wv1.x + xv.z * wv2.x + xv.w * wv3.x;
            acc[i][1] += xv.x * wv0.y + xv.y * wv1.y + xv.z * wv2.y + xv.w * wv3.y;
            acc[i][2] += xv.x * wv0.z + xv.y * wv1.z + xv.z * wv2.z + xv.w * wv3.z;
            acc[i][3] += xv.x * wv0.w + xv.y * wv1.w + xv.z * wv2.w + xv.w * wv3.w;
        }
    }

    const float a = pa[0];
    const float4 bv = ((const float4*)bias)[tn];

    #pragma unroll
    for (int i = 0; i < 4; ++i) {
        const int gr = row0 + tm * 4 + i;
        float t0 = acc[i][0] + bv.x;
        float t1 = acc[i][1] + bv.y;
        float t2 = acc[i][2] + bv.z;
        float t3 = acc[i][3] + bv.w;
        float4 r;
        r.x = fmaxf(t0 >= 0.f ? t0 : a * t0, 0.f);
        r.y = fmaxf(t1 >= 0.f ? t1 : a * t1, 0.f);
        r.z = fmaxf(t2 >= 0.f ? t2 : a * t2, 0.f);
        r.w = fmaxf(t3 >= 0.f ? t3 : a * t3, 0.f);
        ((float4*)(out + (size_t)gr * D))[tn] = r;
    }
}

// ---------------------------------------------------------------------------
extern "C" void kernel_launch(void* const* d_in, const int* in_sizes, int n_in,
                              void* d_out, int out_size, void* d_ws, size_t ws_size,
                              hipStream_t stream) {
    const float* x    = (const float*)d_in[0];
    const int*   ei   = (const int*)d_in[1];
    const float* ew   = (const float*)d_in[2];
    const float* W    = (const float*)d_in[3];
    const float* bias = (const float*)d_in[4];
    const float* pa   = (const float*)d_in[5];
    float* out = (float*)d_out;

    // Workspace layout (4B units)
    int* deg      = (int*)d_ws;              // N
    int* off      = deg + N_NODES;           // N+1
    int* cursor   = off + N_NODES + 1;       // N
    int* bsum     = cursor + N_NODES;        // NB
    int* boff     = bsum + NB;               // NB+1
    int2* csr_pair = (int2*)(boff + NB + 2); // E pairs (8B-aligned: offset even)
    const size_t need = (size_t)(3 * N_NODES + 2 + 2 * NB + 2 * N_EDGES + 16) * 4;

    if (ws_size >= need) {
        hipMemsetAsync(deg, 0, (size_t)N_NODES * sizeof(int), stream);
        k_hist  <<<(N_EDGES + 255) / 256, 256, 0, stream>>>(ei, deg);
        k_scan_a<<<NB, 256, 0, stream>>>(deg, off, bsum);
        k_scan_b<<<1, 128, 0, stream>>>(bsum, boff);
        k_scan_c<<<(N_NODES + 256) / 256, 256, 0, stream>>>(off, cursor, boff);
        k_fill  <<<(N_EDGES + 255) / 256, 256, 0, stream>>>(ei, ew, cursor, csr_pair);
        k_gather<<<(N_NODES + 3) / 4, 256, 0, stream>>>(x, off, csr_pair, out);
    } else {
        hipMemsetAsync(out, 0, (size_t)N_NODES * D * sizeof(float), stream);
        gcn_scatter<<<12800, 256, 0, stream>>>(x, ei, ew, out);
    }

    gcn_transform<<<N_NODES / MT, 256, 0, stream>>>(out, W, bias, pa, out);
}

// Round 4
// 381.118 us; speedup vs baseline: 4.0994x; 1.2742x over previous
//
#include <hip/hip_runtime.h>

#define N_NODES 100000
#define N_EDGES 1600000
#define D 128

#define NCB   512                 // coarse buckets
#define BR    196                 // nodes per coarse bucket (196*512 >= N)
#define CHUNK 4096                // edges per k_part block
#define SLOTS 24                  // LDS bin capacity in k_part (lambda=8)
#define CAP   6144                // max pairs per coarse bucket in k_csr (mu=3125, 54 sigma)

// ---------------------------------------------------------------------------
// Pass 0: coarse histogram (LDS-privatized) + single-block scan.
// ---------------------------------------------------------------------------
__global__ __launch_bounds__(256) void k_chist(
    const int* __restrict__ ei, int* __restrict__ ghist)
{
    __shared__ int h[NCB];
    const int t = threadIdx.x;
    h[t] = 0; h[t + 256] = 0;
    __syncthreads();
    const int stride = gridDim.x * blockDim.x;
    for (int e = blockIdx.x * blockDim.x + t; e < N_EDGES; e += stride)
        atomicAdd(&h[ei[N_EDGES + e] / BR], 1);
    __syncthreads();
    atomicAdd(&ghist[t], h[t]);
    atomicAdd(&ghist[t + 256], h[t + 256]);
}

__global__ __launch_bounds__(512) void k_cscan(
    const int* __restrict__ ghist, int* __restrict__ cOff, int* __restrict__ gcur)
{
    __shared__ int sh[NCB];
    const int t = threadIdx.x;
    const int v = ghist[t];
    sh[t] = v;
    __syncthreads();
    for (int d = 1; d < NCB; d <<= 1) {
        int u = (t >= d) ? sh[t - d] : 0;
        __syncthreads();
        sh[t] += u;
        __syncthreads();
    }
    const int excl = sh[t] - v;
    cOff[t] = excl;
    gcur[t] = excl;
    if (t == NCB - 1) cOff[NCB] = sh[NCB - 1];
}

// ---------------------------------------------------------------------------
// Pass 1: partition edges into coarse-bucket regions with LDS binning so
// global writes land in contiguous >=192B runs (vs 8B random scatter).
// Pair packing: x = src | (local_dst << 17)  (src < 2^17, local_dst < 256).
// ---------------------------------------------------------------------------
__global__ __launch_bounds__(256, 1) void k_part(
    const int* __restrict__ ei, const float* __restrict__ ew,
    int* __restrict__ gcur, int2* __restrict__ part)
{
    __shared__ int2 bins[NCB * SLOTS];   // 96 KB
    __shared__ int bcnt[NCB];
    __shared__ int bbase[NCB];
    const int t = threadIdx.x;
    const int e0 = blockIdx.x * CHUNK;

    bcnt[t] = 0; bcnt[t + 256] = 0;
    __syncthreads();

    #pragma unroll
    for (int k = 0; k < CHUNK / 256; ++k) {
        const int e = e0 + k * 256 + t;
        if (e < N_EDGES) {
            const int dst = ei[N_EDGES + e];
            const int src = ei[e];
            const int b = dst / BR;            // magic-mul division
            const int ld = dst - b * BR;
            const int2 p = make_int2(src | (ld << 17), __float_as_int(ew[e]));
            const int r = atomicAdd(&bcnt[b], 1);
            if (r < SLOTS) bins[b * SLOTS + r] = p;
            else {                              // statistical overflow: direct write
                int pos = atomicAdd(&gcur[b], 1);
                part[pos] = p;
            }
        }
    }
    __syncthreads();

    // Bulk reservation: one atomic per non-empty bin.
    {
        int c0 = min(bcnt[t], SLOTS);
        int c1 = min(bcnt[t + 256], SLOTS);
        bbase[t]       = c0 ? atomicAdd(&gcur[t], c0) : 0;
        bbase[t + 256] = c1 ? atomicAdd(&gcur[t + 256], c1) : 0;
        bcnt[t] = c0; bcnt[t + 256] = c1;
    }
    __syncthreads();

    // Copy-out over slot space: consecutive threads -> same-bin runs.
    for (int s = t; s < NCB * SLOTS; s += 256) {
        const int b = s / SLOTS;
        const int r = s - b * SLOTS;
        if (r < bcnt[b]) part[bbase[b] + r] = bins[s];
    }
}

// ---------------------------------------------------------------------------
// Pass 2: one block per coarse bucket. Load pairs to LDS, per-node histogram
// + scan, reorder in LDS, stream back IN PLACE fully coalesced. Also emits
// off[] (exact CSR offsets) for the gather.
// ---------------------------------------------------------------------------
__global__ __launch_bounds__(256, 1) void k_csr(
    const int* __restrict__ cOff, int2* __restrict__ part, int* __restrict__ off)
{
    __shared__ int2 buf[CAP];    // 48 KB
    __shared__ int2 obuf[CAP];   // 48 KB
    __shared__ int nh[256];
    __shared__ int orig[256];
    __shared__ int cur[256];

    const int b = blockIdx.x;
    const int t = threadIdx.x;
    const int lo = b * BR;
    const int base = cOff[b];
    int cnt = cOff[b + 1] - base;
    if (cnt > CAP) cnt = CAP;    // unreachable for this input (54 sigma); guards LDS

    nh[t] = 0;
    __syncthreads();

    for (int i = t; i < cnt; i += 256) {
        const int2 p = part[base + i];
        buf[i] = p;
        atomicAdd(&nh[((unsigned)p.x) >> 17], 1);
    }
    __syncthreads();
    orig[t] = nh[t];
    __syncthreads();
    for (int d = 1; d < 256; d <<= 1) {
        int u = (t >= d) ? nh[t - d] : 0;
        __syncthreads();
        nh[t] += u;
        __syncthreads();
    }
    const int excl = nh[t] - orig[t];
    cur[t] = excl;
    if (t < BR && lo + t < N_NODES) off[lo + t] = base + excl;
    if (b == NCB - 1 && t == 0) off[N_NODES] = cOff[NCB];
    __syncthreads();

    for (int i = t; i < cnt; i += 256) {
        const int2 p = buf[i];
        const int ld = ((unsigned)p.x) >> 17;
        const int r = atomicAdd(&cur[ld], 1);
        obuf[r] = make_int2(p.x & 0x1FFFF, p.y);
    }
    __syncthreads();
    for (int i = t; i < cnt; i += 256)
        part[base + i] = obuf[i];
}

// ---------------------------------------------------------------------------
// Gather: one wave per node, lanes hold 2 consecutive floats, 4-deep unroll.
// ---------------------------------------------------------------------------
__global__ __launch_bounds__(256) void k_gather(
    const float* __restrict__ x, const int* __restrict__ off,
    const int2* __restrict__ csr_pair, float* __restrict__ agg)
{
    const int lane = threadIdx.x & 63;
    const int n = (blockIdx.x * blockDim.x + threadIdx.x) >> 6;
    if (n >= N_NODES) return;

    const int beg = off[n];
    const int end = off[n + 1];
    const float2* __restrict__ x2 = (const float2*)x;

    float2 acc = make_float2(0.f, 0.f);
    int e = beg;
    for (; e + 4 <= end; e += 4) {
        const int2 p0 = csr_pair[e + 0], p1 = csr_pair[e + 1];
        const int2 p2 = csr_pair[e + 2], p3 = csr_pair[e + 3];
        const float2 v0 = x2[(size_t)p0.x * 64 + lane];
        const float2 v1 = x2[(size_t)p1.x * 64 + lane];
        const float2 v2 = x2[(size_t)p2.x * 64 + lane];
        const float2 v3 = x2[(size_t)p3.x * 64 + lane];
        const float w0 = __int_as_float(p0.y), w1 = __int_as_float(p1.y);
        const float w2 = __int_as_float(p2.y), w3 = __int_as_float(p3.y);
        acc.x += w0 * v0.x + w1 * v1.x + w2 * v2.x + w3 * v3.x;
        acc.y += w0 * v0.y + w1 * v1.y + w2 * v2.y + w3 * v3.y;
    }
    for (; e < end; ++e) {
        const int2 p = csr_pair[e];
        const float w = __int_as_float(p.y);
        const float2 v = x2[(size_t)p.x * 64 + lane];
        acc.x += w * v.x;
        acc.y += w * v.y;
    }
    ((float2*)agg)[(size_t)n * 64 + lane] = acc;
}

// ---------------------------------------------------------------------------
// Fallback scatter (only if ws too small) — proven correct in R1.
// ---------------------------------------------------------------------------
__global__ __launch_bounds__(256) void gcn_scatter(
    const float* __restrict__ x, const int* __restrict__ ei,
    const float* __restrict__ ew, float* __restrict__ agg)
{
    const int lane = threadIdx.x & 63;
    const int wave = (blockIdx.x * blockDim.x + threadIdx.x) >> 6;
    const int nwaves = (gridDim.x * blockDim.x) >> 6;
    for (int e = wave; e < N_EDGES; e += nwaves) {
        const int src = ei[e];
        const int dst = ei[N_EDGES + e];
        const float w = ew[e];
        const float2 v = ((const float2*)(x + (size_t)src * D))[lane];
        float* op = agg + (size_t)dst * D + lane * 2;
        unsafeAtomicAdd(op,     w * v.x);
        unsafeAtomicAdd(op + 1, w * v.y);
    }
}

// ---------------------------------------------------------------------------
// Fused transform: out = relu(prelu(agg @ W^T + bias, a)) — in place.
// ---------------------------------------------------------------------------
#define MT 32

__global__ __launch_bounds__(256, 2) void gcn_transform(
    const float* __restrict__ A, const float* __restrict__ W,
    const float* __restrict__ bias, const float* __restrict__ pa,
    float* __restrict__ out)
{
    __shared__ float Wt[D][D];      // Wt[k][n] = W[n][k]
    __shared__ float xs[MT][D];

    const int tid = threadIdx.x;
    const int row0 = blockIdx.x * MT;

    // Lane-consecutive n -> LDS write banks 0..31, conflict-free staging.
    for (int j = tid; j < D * (D / 4); j += 256) {
        const int n = j & 127;
        const int kg = j >> 7;
        const float4 v = ((const float4*)W)[n * (D / 4) + kg];
        const int k4 = kg << 2;
        Wt[k4 + 0][n] = v.x;
        Wt[k4 + 1][n] = v.y;
        Wt[k4 + 2][n] = v.z;
        Wt[k4 + 3][n] = v.w;
    }
    for (int i = tid; i < MT * (D / 4); i += 256) {
        const int r = i >> 5;
        const int c4 = i & 31;
        ((float4*)xs[r])[c4] = ((const float4*)(A + (size_t)(row0 + r) * D))[c4];
    }
    __syncthreads();

    const int tn = tid & 31;
    const int tm = tid >> 5;
    float acc[4][4] = {};

    #pragma unroll
    for (int k = 0; k < D; k += 4) {
        const float4 wv0 = *(const float4*)&Wt[k + 0][tn * 4];
        const float4 wv1 = *(const float4*)&Wt[k + 1][tn * 4];
        const float4 wv2 = *(const float4*)&Wt[k + 2][tn * 4];
        const float4 wv3 = *(const float4*)&Wt[k + 3][tn * 4];
        #pragma unroll
        for (int i = 0; i < 4; ++i) {
            const float4 xv = *(const float4*)&xs[tm * 4 + i][k];
            acc[i][0] += xv.x * wv0.x + xv.y * wv1.x + xv.z * wv2.x + xv.w * wv3.x;
            acc[i][1] += xv.x * wv0.y + xv.y * wv1.y + xv.z * wv2.y + xv.w * wv3.y;
            acc[i][2] += xv.x * wv0.z + xv.y * wv1.z + xv.z * wv2.z + xv.w * wv3.z;
            acc[i][3] += xv.x * wv0.w + xv.y * wv1.w + xv.z * wv2.w + xv.w * wv3.w;
        }
    }

    const float a = pa[0];
    const float4 bv = ((const float4*)bias)[tn];

    #pragma unroll
    for (int i = 0; i < 4; ++i) {
        const int gr = row0 + tm * 4 + i;
        float t0 = acc[i][0] + bv.x;
        float t1 = acc[i][1] + bv.y;
        float t2 = acc[i][2] + bv.z;
        float t3 = acc[i][3] + bv.w;
        float4 r;
        r.x = fmaxf(t0 >= 0.f ? t0 : a * t0, 0.f);
        r.y = fmaxf(t1 >= 0.f ? t1 : a * t1, 0.f);
        r.z = fmaxf(t2 >= 0.f ? t2 : a * t2, 0.f);
        r.w = fmaxf(t3 >= 0.f ? t3 : a * t3, 0.f);
        ((float4*)(out + (size_t)gr * D))[tn] = r;
    }
}

// ---------------------------------------------------------------------------
extern "C" void kernel_launch(void* const* d_in, const int* in_sizes, int n_in,
                              void* d_out, int out_size, void* d_ws, size_t ws_size,
                              hipStream_t stream) {
    const float* x    = (const float*)d_in[0];
    const int*   ei   = (const int*)d_in[1];
    const float* ew   = (const float*)d_in[2];
    const float* W    = (const float*)d_in[3];
    const float* bias = (const float*)d_in[4];
    const float* pa   = (const float*)d_in[5];
    float* out = (float*)d_out;

    // Workspace layout (4B units)
    int* ghist = (int*)d_ws;             // NCB
    int* cOff  = ghist + NCB;            // NCB+1
    int* gcur  = cOff + NCB + 1;         // NCB
    int* off   = gcur + NCB;             // N+1
    int* p0    = off + N_NODES + 1;      // running total: 512+513+512+100001 = 101538 (even -> 8B aligned)
    int2* part = (int2*)p0;              // E pairs (sorted in place by k_csr)
    const size_t need = (size_t)(3 * NCB + 2 + N_NODES + 2 * N_EDGES + 16) * 4;

    if (ws_size >= need) {
        hipMemsetAsync(ghist, 0, NCB * sizeof(int), stream);
        k_chist<<<1024, 256, 0, stream>>>(ei, ghist);
        k_cscan<<<1, NCB, 0, stream>>>(ghist, cOff, gcur);
        k_part <<<(N_EDGES + CHUNK - 1) / CHUNK, 256, 0, stream>>>(ei, ew, gcur, part);
        k_csr  <<<NCB, 256, 0, stream>>>(cOff, part, off);
        k_gather<<<(N_NODES + 3) / 4, 256, 0, stream>>>(x, off, part, out);
    } else {
        hipMemsetAsync(out, 0, (size_t)N_NODES * D * sizeof(float), stream);
        gcn_scatter<<<12800, 256, 0, stream>>>(x, ei, ew, out);
    }

    gcn_transform<<<N_NODES / MT, 256, 0, stream>>>(out, W, bias, pa, out);
}

// Round 5
// 317.608 us; speedup vs baseline: 4.9191x; 1.2000x over previous
//
#include <hip/hip_runtime.h>

#define N_NODES 100000
#define N_EDGES 1600000
#define D 128

#define NCB   512                 // coarse buckets
#define BR    196                 // nodes per coarse bucket
#define CHUNK 4096                // edges per k_part block
#define SLOTS 24                  // LDS bin capacity in k_part
#define CAP   6144                // max pairs per coarse bucket in k_csr

typedef __bf16 bf16x8 __attribute__((ext_vector_type(8)));
typedef float  f32x4  __attribute__((ext_vector_type(4)));

static __device__ __forceinline__ unsigned short f2bf(float f) {
    union { float f; unsigned u; } v; v.f = f;
    unsigned r = v.u + 0x7FFFu + ((v.u >> 16) & 1u);   // RNE
    return (unsigned short)(r >> 16);
}
static __device__ __forceinline__ __bf16 bfbits(unsigned short s) {
    union { unsigned short u; __bf16 h; } v; v.u = s; return v.h;
}

// ---------------------------------------------------------------------------
// fp32 -> bf16 cast (generic, float4 -> ushort4 per thread).
// ---------------------------------------------------------------------------
__global__ __launch_bounds__(256) void k_cast(
    const float4* __restrict__ src, ushort4* __restrict__ dst, int nquads)
{
    const int i = blockIdx.x * blockDim.x + threadIdx.x;
    if (i >= nquads) return;
    const float4 v = src[i];
    dst[i] = make_ushort4(f2bf(v.x), f2bf(v.y), f2bf(v.z), f2bf(v.w));
}

// ---------------------------------------------------------------------------
// Pass 0: coarse histogram (LDS-privatized) + single-block scan.
// ---------------------------------------------------------------------------
__global__ __launch_bounds__(256) void k_chist(
    const int* __restrict__ ei, int* __restrict__ ghist)
{
    __shared__ int h[NCB];
    const int t = threadIdx.x;
    h[t] = 0; h[t + 256] = 0;
    __syncthreads();
    const int stride = gridDim.x * blockDim.x;
    for (int e = blockIdx.x * blockDim.x + t; e < N_EDGES; e += stride)
        atomicAdd(&h[ei[N_EDGES + e] / BR], 1);
    __syncthreads();
    atomicAdd(&ghist[t], h[t]);
    atomicAdd(&ghist[t + 256], h[t + 256]);
}

__global__ __launch_bounds__(512) void k_cscan(
    const int* __restrict__ ghist, int* __restrict__ cOff, int* __restrict__ gcur)
{
    __shared__ int sh[NCB];
    const int t = threadIdx.x;
    const int v = ghist[t];
    sh[t] = v;
    __syncthreads();
    for (int d = 1; d < NCB; d <<= 1) {
        int u = (t >= d) ? sh[t - d] : 0;
        __syncthreads();
        sh[t] += u;
        __syncthreads();
    }
    const int excl = sh[t] - v;
    cOff[t] = excl;
    gcur[t] = excl;
    if (t == NCB - 1) cOff[NCB] = sh[NCB - 1];
}

// ---------------------------------------------------------------------------
// Pass 1: partition edges into coarse-bucket regions with LDS binning.
// Pair packing: x = src | (local_dst << 17).
// ---------------------------------------------------------------------------
__global__ __launch_bounds__(256, 1) void k_part(
    const int* __restrict__ ei, const float* __restrict__ ew,
    int* __restrict__ gcur, int2* __restrict__ part)
{
    __shared__ int2 bins[NCB * SLOTS];   // 96 KB
    __shared__ int bcnt[NCB];
    __shared__ int bbase[NCB];
    const int t = threadIdx.x;
    const int e0 = blockIdx.x * CHUNK;

    bcnt[t] = 0; bcnt[t + 256] = 0;
    __syncthreads();

    #pragma unroll
    for (int k = 0; k < CHUNK / 256; ++k) {
        const int e = e0 + k * 256 + t;
        if (e < N_EDGES) {
            const int dst = ei[N_EDGES + e];
            const int src = ei[e];
            const int b = dst / BR;
            const int ld = dst - b * BR;
            const int2 p = make_int2(src | (ld << 17), __float_as_int(ew[e]));
            const int r = atomicAdd(&bcnt[b], 1);
            if (r < SLOTS) bins[b * SLOTS + r] = p;
            else {
                int pos = atomicAdd(&gcur[b], 1);
                part[pos] = p;
            }
        }
    }
    __syncthreads();

    {
        int c0 = min(bcnt[t], SLOTS);
        int c1 = min(bcnt[t + 256], SLOTS);
        bbase[t]       = c0 ? atomicAdd(&gcur[t], c0) : 0;
        bbase[t + 256] = c1 ? atomicAdd(&gcur[t + 256], c1) : 0;
        bcnt[t] = c0; bcnt[t + 256] = c1;
    }
    __syncthreads();

    for (int s = t; s < NCB * SLOTS; s += 256) {
        const int b = s / SLOTS;
        const int r = s - b * SLOTS;
        if (r < bcnt[b]) part[bbase[b] + r] = bins[s];
    }
}

// ---------------------------------------------------------------------------
// Pass 2: per-bucket LDS sort -> in-place CSR + off[].
// ---------------------------------------------------------------------------
__global__ __launch_bounds__(256, 1) void k_csr(
    const int* __restrict__ cOff, int2* __restrict__ part, int* __restrict__ off)
{
    __shared__ int2 buf[CAP];    // 48 KB
    __shared__ int2 obuf[CAP];   // 48 KB
    __shared__ int nh[256];
    __shared__ int orig[256];
    __shared__ int cur[256];

    const int b = blockIdx.x;
    const int t = threadIdx.x;
    const int lo = b * BR;
    const int base = cOff[b];
    int cnt = cOff[b + 1] - base;
    if (cnt > CAP) cnt = CAP;

    nh[t] = 0;
    __syncthreads();

    for (int i = t; i < cnt; i += 256) {
        const int2 p = part[base + i];
        buf[i] = p;
        atomicAdd(&nh[((unsigned)p.x) >> 17], 1);
    }
    __syncthreads();
    orig[t] = nh[t];
    __syncthreads();
    for (int d = 1; d < 256; d <<= 1) {
        int u = (t >= d) ? nh[t - d] : 0;
        __syncthreads();
        nh[t] += u;
        __syncthreads();
    }
    const int excl = nh[t] - orig[t];
    cur[t] = excl;
    if (t < BR && lo + t < N_NODES) off[lo + t] = base + excl;
    if (b == NCB - 1 && t == 0) off[N_NODES] = cOff[NCB];
    __syncthreads();

    for (int i = t; i < cnt; i += 256) {
        const int2 p = buf[i];
        const int ld = ((unsigned)p.x) >> 17;
        const int r = atomicAdd(&cur[ld], 1);
        obuf[r] = make_int2(p.x & 0x1FFFF, p.y);
    }
    __syncthreads();
    for (int i = t; i < cnt; i += 256)
        part[base + i] = obuf[i];
}

// ---------------------------------------------------------------------------
// Gather (bf16 x): one wave per node; lane reads one uint = 2 bf16 per edge
// (256B per row vs 512B fp32 -> halves scattered-line traffic). fp32 accum,
// writes fp32 agg row.
// ---------------------------------------------------------------------------
__global__ __launch_bounds__(256) void k_gather_h(
    const unsigned int* __restrict__ xh, const int* __restrict__ off,
    const int2* __restrict__ csr_pair, float* __restrict__ agg)
{
    const int lane = threadIdx.x & 63;
    const int n = (blockIdx.x * blockDim.x + threadIdx.x) >> 6;
    if (n >= N_NODES) return;

    const int beg = off[n];
    const int end = off[n + 1];

    float ax = 0.f, ay = 0.f;
    int e = beg;
    for (; e + 4 <= end; e += 4) {
        const int2 p0 = csr_pair[e + 0], p1 = csr_pair[e + 1];
        const int2 p2 = csr_pair[e + 2], p3 = csr_pair[e + 3];
        const unsigned u0 = xh[(size_t)p0.x * 64 + lane];
        const unsigned u1 = xh[(size_t)p1.x * 64 + lane];
        const unsigned u2 = xh[(size_t)p2.x * 64 + lane];
        const unsigned u3 = xh[(size_t)p3.x * 64 + lane];
        const float w0 = __int_as_float(p0.y), w1 = __int_as_float(p1.y);
        const float w2 = __int_as_float(p2.y), w3 = __int_as_float(p3.y);
        ax += w0 * __uint_as_float(u0 << 16) + w1 * __uint_as_float(u1 << 16)
            + w2 * __uint_as_float(u2 << 16) + w3 * __uint_as_float(u3 << 16);
        ay += w0 * __uint_as_float(u0 & 0xFFFF0000u) + w1 * __uint_as_float(u1 & 0xFFFF0000u)
            + w2 * __uint_as_float(u2 & 0xFFFF0000u) + w3 * __uint_as_float(u3 & 0xFFFF0000u);
    }
    for (; e < end; ++e) {
        const int2 p = csr_pair[e];
        const float w = __int_as_float(p.y);
        const unsigned u = xh[(size_t)p.x * 64 + lane];
        ax += w * __uint_as_float(u << 16);
        ay += w * __uint_as_float(u & 0xFFFF0000u);
    }
    ((float2*)agg)[(size_t)n * 64 + lane] = make_float2(ax, ay);
}

// fp32 gather (tier B fallback — R4-proven).
__global__ __launch_bounds__(256) void k_gather(
    const float* __restrict__ x, const int* __restrict__ off,
    const int2* __restrict__ csr_pair, float* __restrict__ agg)
{
    const int lane = threadIdx.x & 63;
    const int n = (blockIdx.x * blockDim.x + threadIdx.x) >> 6;
    if (n >= N_NODES) return;
    const int beg = off[n], end = off[n + 1];
    const float2* __restrict__ x2 = (const float2*)x;
    float2 acc = make_float2(0.f, 0.f);
    int e = beg;
    for (; e + 4 <= end; e += 4) {
        const int2 p0 = csr_pair[e + 0], p1 = csr_pair[e + 1];
        const int2 p2 = csr_pair[e + 2], p3 = csr_pair[e + 3];
        const float2 v0 = x2[(size_t)p0.x * 64 + lane];
        const float2 v1 = x2[(size_t)p1.x * 64 + lane];
        const float2 v2 = x2[(size_t)p2.x * 64 + lane];
        const float2 v3 = x2[(size_t)p3.x * 64 + lane];
        const float w0 = __int_as_float(p0.y), w1 = __int_as_float(p1.y);
        const float w2 = __int_as_float(p2.y), w3 = __int_as_float(p3.y);
        acc.x += w0 * v0.x + w1 * v1.x + w2 * v2.x + w3 * v3.x;
        acc.y += w0 * v0.y + w1 * v1.y + w2 * v2.y + w3 * v3.y;
    }
    for (; e < end; ++e) {
        const int2 p = csr_pair[e];
        const float w = __int_as_float(p.y);
        const float2 v = x2[(size_t)p.x * 64 + lane];
        acc.x += w * v.x;
        acc.y += w * v.y;
    }
    ((float2*)agg)[(size_t)n * 64 + lane] = acc;
}

// ---------------------------------------------------------------------------
// MFMA transform: out = relu(prelu(agg @ W^T + bias, a)), in place.
// One wave per 16 nodes x 128 cols. A-frags: fp32 agg rows cvt->bf16 in regs
// (rows private to the wave -> in-place safe; all A reads precede stores).
// Layouts (16x16x32 bf16, verified m89/m91): A[m=lane&15][k=quad*8+j],
// B[n=lane&15][k=quad*8+j], C: col=lane&15, row=quad*4+reg.
// ---------------------------------------------------------------------------
__global__ __launch_bounds__(256) void k_xform(
    const float* __restrict__ A,            // fp32 agg (aliases out)
    const unsigned short* __restrict__ wh,  // bf16 W row-major [n][k]
    const float* __restrict__ bias, const float* __restrict__ pa,
    float* __restrict__ out)
{
    const int tid = threadIdx.x;
    const int lane = tid & 63;
    const int wid = (blockIdx.x << 2) + (tid >> 6);
    const int m0 = wid << 4;
    if (m0 >= N_NODES) return;
    const int mm = lane & 15;
    const int quad = lane >> 4;
    const float aP = pa[0];

    bf16x8 af[4];
    {
        const float* rowp = A + (size_t)(m0 + mm) * D + quad * 8;
        #pragma unroll
        for (int c = 0; c < 4; ++c) {
            const float4 v0 = *(const float4*)(rowp + 32 * c);
            const float4 v1 = *(const float4*)(rowp + 32 * c + 4);
            af[c][0] = bfbits(f2bf(v0.x)); af[c][1] = bfbits(f2bf(v0.y));
            af[c][2] = bfbits(f2bf(v0.z)); af[c][3] = bfbits(f2bf(v0.w));
            af[c][4] = bfbits(f2bf(v1.x)); af[c][5] = bfbits(f2bf(v1.y));
            af[c][6] = bfbits(f2bf(v1.z)); af[c][7] = bfbits(f2bf(v1.w));
        }
    }

    #pragma unroll
    for (int t = 0; t < 8; ++t) {
        const int n = (t << 4) + mm;
        f32x4 acc = {0.f, 0.f, 0.f, 0.f};
        #pragma unroll
        for (int c = 0; c < 4; ++c) {
            const bf16x8 bf = *(const bf16x8*)(wh + n * D + 32 * c + quad * 8);
            acc = __builtin_amdgcn_mfma_f32_16x16x32_bf16(af[c], bf, acc, 0, 0, 0);
        }
        const float bv = bias[n];
        #pragma unroll
        for (int r = 0; r < 4; ++r) {
            float v = acc[r] + bv;
            v = (v >= 0.f) ? v : aP * v;
            v = fmaxf(v, 0.f);
            out[(size_t)(m0 + (quad << 2) + r) * D + n] = v;
        }
    }
}

// ---------------------------------------------------------------------------
// Tier-C fallbacks (tiny ws): atomic scatter + fp32 vector transform.
// ---------------------------------------------------------------------------
__global__ __launch_bounds__(256) void gcn_scatter(
    const float* __restrict__ x, const int* __restrict__ ei,
    const float* __restrict__ ew, float* __restrict__ agg)
{
    const int lane = threadIdx.x & 63;
    const int wave = (blockIdx.x * blockDim.x + threadIdx.x) >> 6;
    const int nwaves = (gridDim.x * blockDim.x) >> 6;
    for (int e = wave; e < N_EDGES; e += nwaves) {
        const int src = ei[e];
        const int dst = ei[N_EDGES + e];
        const float w = ew[e];
        const float2 v = ((const float2*)(x + (size_t)src * D))[lane];
        float* op = agg + (size_t)dst * D + lane * 2;
        unsafeAtomicAdd(op,     w * v.x);
        unsafeAtomicAdd(op + 1, w * v.y);
    }
}

#define MT 32
__global__ __launch_bounds__(256, 2) void gcn_transform(
    const float* __restrict__ A, const float* __restrict__ W,
    const float* __restrict__ bias, const float* __restrict__ pa,
    float* __restrict__ out)
{
    __shared__ float Wt[D][D];
    __shared__ float xs[MT][D];
    const int tid = threadIdx.x;
    const int row0 = blockIdx.x * MT;

    for (int j = tid; j < D * (D / 4); j += 256) {
        const int n = j & 127;
        const int kg = j >> 7;
        const float4 v = ((const float4*)W)[n * (D / 4) + kg];
        const int k4 = kg << 2;
        Wt[k4 + 0][n] = v.x; Wt[k4 + 1][n] = v.y;
        Wt[k4 + 2][n] = v.z; Wt[k4 + 3][n] = v.w;
    }
    for (int i = tid; i < MT * (D / 4); i += 256) {
        const int r = i >> 5;
        const int c4 = i & 31;
        ((float4*)xs[r])[c4] = ((const float4*)(A + (size_t)(row0 + r) * D))[c4];
    }
    __syncthreads();

    const int tn = tid & 31;
    const int tm = tid >> 5;
    float acc[4][4] = {};
    #pragma unroll
    for (int k = 0; k < D; k += 4) {
        const float4 wv0 = *(const float4*)&Wt[k + 0][tn * 4];
        const float4 wv1 = *(const float4*)&Wt[k + 1][tn * 4];
        const float4 wv2 = *(const float4*)&Wt[k + 2][tn * 4];
        const float4 wv3 = *(const float4*)&Wt[k + 3][tn * 4];
        #pragma unroll
        for (int i = 0; i < 4; ++i) {
            const float4 xv = *(const float4*)&xs[tm * 4 + i][k];
            acc[i][0] += xv.x * wv0.x + xv.y * wv1.x + xv.z * wv2.x + xv.w * wv3.x;
            acc[i][1] += xv.x * wv0.y + xv.y * wv1.y + xv.z * wv2.y + xv.w * wv3.y;
            acc[i][2] += xv.x * wv0.z + xv.y * wv1.z + xv.z * wv2.z + xv.w * wv3.z;
            acc[i][3] += xv.x * wv0.w + xv.y * wv1.w + xv.z * wv2.w + xv.w * wv3.w;
        }
    }
    const float a = pa[0];
    const float4 bv = ((const float4*)bias)[tn];
    #pragma unroll
    for (int i = 0; i < 4; ++i) {
        const int gr = row0 + tm * 4 + i;
        float t0 = acc[i][0] + bv.x, t1 = acc[i][1] + bv.y;
        float t2 = acc[i][2] + bv.z, t3 = acc[i][3] + bv.w;
        float4 r;
        r.x = fmaxf(t0 >= 0.f ? t0 : a * t0, 0.f);
        r.y = fmaxf(t1 >= 0.f ? t1 : a * t1, 0.f);
        r.z = fmaxf(t2 >= 0.f ? t2 : a * t2, 0.f);
        r.w = fmaxf(t3 >= 0.f ? t3 : a * t3, 0.f);
        ((float4*)(out + (size_t)gr * D))[tn] = r;
    }
}

// ---------------------------------------------------------------------------
extern "C" void kernel_launch(void* const* d_in, const int* in_sizes, int n_in,
                              void* d_out, int out_size, void* d_ws, size_t ws_size,
                              hipStream_t stream) {
    const float* x    = (const float*)d_in[0];
    const int*   ei   = (const int*)d_in[1];
    const float* ew   = (const float*)d_in[2];
    const float* W    = (const float*)d_in[3];
    const float* bias = (const float*)d_in[4];
    const float* pa   = (const float*)d_in[5];
    float* out = (float*)d_out;

    // Workspace layout (int units)
    const size_t o_ghist = 0;
    const size_t o_cOff  = o_ghist + NCB;               // 512
    const size_t o_gcur  = o_cOff + NCB + 1;            // 1025
    const size_t o_off   = o_gcur + NCB;                // 1537
    const size_t o_part  = o_off + N_NODES + 1;         // 101538 (8B-aligned)
    const size_t o_wh    = (o_part + 2 * (size_t)N_EDGES + 3) & ~(size_t)3; // 16B-aligned
    const size_t o_xh    = o_wh + (size_t)D * D / 2;    // 16B-aligned
    const size_t endA    = o_xh + (size_t)N_NODES * D / 2;
    const size_t needA = endA * 4;
    const size_t needB = o_xh * 4;

    int* wsb = (int*)d_ws;
    int* ghist = wsb + o_ghist;
    int* cOff  = wsb + o_cOff;
    int* gcur  = wsb + o_gcur;
    int* off   = wsb + o_off;
    int2* part = (int2*)(wsb + o_part);
    unsigned short* wh = (unsigned short*)(wsb + o_wh);
    unsigned short* xh = (unsigned short*)(wsb + o_xh);

    if (ws_size >= needB) {
        hipMemsetAsync(ghist, 0, NCB * sizeof(int), stream);
        const bool tierA = (ws_size >= needA);
        if (tierA)
            k_cast<<<(N_NODES * D / 4 + 255) / 256, 256, 0, stream>>>(
                (const float4*)x, (ushort4*)xh, N_NODES * D / 4);
        k_cast<<<(D * D / 4 + 255) / 256, 256, 0, stream>>>(
            (const float4*)W, (ushort4*)wh, D * D / 4);
        k_chist<<<1024, 256, 0, stream>>>(ei, ghist);
        k_cscan<<<1, NCB, 0, stream>>>(ghist, cOff, gcur);
        k_part <<<(N_EDGES + CHUNK - 1) / CHUNK, 256, 0, stream>>>(ei, ew, gcur, part);
        k_csr  <<<NCB, 256, 0, stream>>>(cOff, part, off);
        if (tierA)
            k_gather_h<<<N_NODES / 4, 256, 0, stream>>>((const unsigned*)xh, off, part, out);
        else
            k_gather<<<N_NODES / 4, 256, 0, stream>>>(x, off, part, out);
        k_xform<<<(N_NODES / 16 + 3) / 4, 256, 0, stream>>>(out, wh, bias, pa, out);
    } else {
        hipMemsetAsync(out, 0, (size_t)N_NODES * D * sizeof(float), stream);
        gcn_scatter<<<12800, 256, 0, stream>>>(x, ei, ew, out);
        gcn_transform<<<N_NODES / MT, 256, 0, stream>>>(out, W, bias, pa, out);
    }
}

// Round 8
// 294.084 us; speedup vs baseline: 5.3126x; 1.0800x over previous
//
#include <hip/hip_runtime.h>

#define N_NODES 100000
#define N_EDGES 1600000
#define D 128

#define NCB   512                 // coarse buckets
#define BR    196                 // nodes per coarse bucket
#define CHUNK 4096                // edges per k_part block
#define SLOTS 24                  // LDS bin capacity in k_part
#define CAP   6144                // max pairs per coarse bucket in k_csr

#define XQ   (N_NODES * D / 4)    // x float4 quads = 3,200,000
#define XQB  (XQ / 256)           // 12500 blocks (exact)
#define WQ   (D * D / 4)          // 4096
#define WQB  (WQ / 256)           // 16 blocks (exact)
#define HB   1024                 // histogram blocks

typedef __bf16 bf16x8 __attribute__((ext_vector_type(8)));
typedef float  f32x4  __attribute__((ext_vector_type(4)));

static __device__ __forceinline__ unsigned short f2bf(float f) {
    union { float f; unsigned u; } v; v.f = f;
    unsigned r = v.u + 0x7FFFu + ((v.u >> 16) & 1u);   // RNE
    return (unsigned short)(r >> 16);
}
static __device__ __forceinline__ __bf16 bfbits(unsigned short s) {
    union { unsigned short u; __bf16 h; } v; v.u = s; return v.h;
}

// ---------------------------------------------------------------------------
// k_prep: fused x->bf16 cast | W->bf16 cast | coarse dst histogram.
// Block ranges: [0,XQB) x-cast, [XQB,XQB+WQB) W-cast, rest histogram.
// ---------------------------------------------------------------------------
__global__ __launch_bounds__(256) void k_prep(
    const float4* __restrict__ x4, ushort4* __restrict__ xh4,
    const float4* __restrict__ w4, ushort4* __restrict__ wh4,
    const int* __restrict__ ei, int* __restrict__ ghist)
{
    __shared__ int h[NCB];
    const int b = blockIdx.x;
    const int t = threadIdx.x;
    if (b < XQB) {
        const int i = b * 256 + t;
        const float4 v = x4[i];
        xh4[i] = make_ushort4(f2bf(v.x), f2bf(v.y), f2bf(v.z), f2bf(v.w));
    } else if (b < XQB + WQB) {
        const int i = (b - XQB) * 256 + t;
        const float4 v = w4[i];
        wh4[i] = make_ushort4(f2bf(v.x), f2bf(v.y), f2bf(v.z), f2bf(v.w));
    } else {
        const int hb = b - XQB - WQB;
        h[t] = 0; h[t + 256] = 0;
        __syncthreads();
        for (int e = hb * 256 + t; e < N_EDGES; e += HB * 256)
            atomicAdd(&h[ei[N_EDGES + e] / BR], 1);
        __syncthreads();
        atomicAdd(&ghist[t], h[t]);
        atomicAdd(&ghist[t + 256], h[t + 256]);
    }
}

__global__ __launch_bounds__(512) void k_cscan(
    const int* __restrict__ ghist, int* __restrict__ cOff, int* __restrict__ gcur)
{
    __shared__ int sh[NCB];
    const int t = threadIdx.x;
    const int v = ghist[t];
    sh[t] = v;
    __syncthreads();
    for (int d = 1; d < NCB; d <<= 1) {
        int u = (t >= d) ? sh[t - d] : 0;
        __syncthreads();
        sh[t] += u;
        __syncthreads();
    }
    const int excl = sh[t] - v;
    cOff[t] = excl;
    gcur[t] = excl;
    if (t == NCB - 1) cOff[NCB] = sh[NCB - 1];
}

// ---------------------------------------------------------------------------
// Pass 1: partition edges into coarse-bucket regions with LDS binning so
// global writes land in contiguous runs. Pair packing: src | (local_dst<<17).
// ---------------------------------------------------------------------------
__global__ __launch_bounds__(256, 1) void k_part(
    const int* __restrict__ ei, const float* __restrict__ ew,
    int* __restrict__ gcur, int2* __restrict__ part)
{
    __shared__ int2 bins[NCB * SLOTS];   // 96 KB
    __shared__ int bcnt[NCB];
    __shared__ int bbase[NCB];
    const int t = threadIdx.x;
    const int e0 = blockIdx.x * CHUNK;

    bcnt[t] = 0; bcnt[t + 256] = 0;
    __syncthreads();

    #pragma unroll
    for (int k = 0; k < CHUNK / 256; ++k) {
        const int e = e0 + k * 256 + t;
        if (e < N_EDGES) {
            const int dst = ei[N_EDGES + e];
            const int src = ei[e];
            const int b = dst / BR;
            const int ld = dst - b * BR;
            const int2 p = make_int2(src | (ld << 17), __float_as_int(ew[e]));
            const int r = atomicAdd(&bcnt[b], 1);
            if (r < SLOTS) bins[b * SLOTS + r] = p;
            else {
                int pos = atomicAdd(&gcur[b], 1);
                part[pos] = p;
            }
        }
    }
    __syncthreads();

    {
        int c0 = min(bcnt[t], SLOTS);
        int c1 = min(bcnt[t + 256], SLOTS);
        bbase[t]       = c0 ? atomicAdd(&gcur[t], c0) : 0;
        bbase[t + 256] = c1 ? atomicAdd(&gcur[t + 256], c1) : 0;
        bcnt[t] = c0; bcnt[t + 256] = c1;
    }
    __syncthreads();

    for (int s = t; s < NCB * SLOTS; s += 256) {
        const int b = s / SLOTS;
        const int r = s - b * SLOTS;
        if (r < bcnt[b]) part[bbase[b] + r] = bins[s];
    }
}

// ---------------------------------------------------------------------------
// Pass 2: per-bucket LDS sort -> in-place CSR + off[].
// ---------------------------------------------------------------------------
__global__ __launch_bounds__(256, 1) void k_csr(
    const int* __restrict__ cOff, int2* __restrict__ part, int* __restrict__ off)
{
    __shared__ int2 buf[CAP];    // 48 KB
    __shared__ int2 obuf[CAP];   // 48 KB
    __shared__ int nh[256];
    __shared__ int orig[256];
    __shared__ int cur[256];

    const int b = blockIdx.x;
    const int t = threadIdx.x;
    const int lo = b * BR;
    const int base = cOff[b];
    int cnt = cOff[b + 1] - base;
    if (cnt > CAP) cnt = CAP;    // unreachable statistically; guards LDS

    nh[t] = 0;
    __syncthreads();

    for (int i = t; i < cnt; i += 256) {
        const int2 p = part[base + i];
        buf[i] = p;
        atomicAdd(&nh[((unsigned)p.x) >> 17], 1);
    }
    __syncthreads();
    orig[t] = nh[t];
    __syncthreads();
    for (int d = 1; d < 256; d <<= 1) {
        int u = (t >= d) ? nh[t - d] : 0;
        __syncthreads();
        nh[t] += u;
        __syncthreads();
    }
    const int excl = nh[t] - orig[t];
    cur[t] = excl;
    if (t < BR && lo + t < N_NODES) off[lo + t] = base + excl;
    if (b == NCB - 1 && t == 0) off[N_NODES] = cOff[NCB];
    __syncthreads();

    for (int i = t; i < cnt; i += 256) {
        const int2 p = buf[i];
        const int ld = ((unsigned)p.x) >> 17;
        const int r = atomicAdd(&cur[ld], 1);
        obuf[r] = make_int2(p.x & 0x1FFFF, p.y);
    }
    __syncthreads();
    for (int i = t; i < cnt; i += 256)
        part[base + i] = obuf[i];
}

// ---------------------------------------------------------------------------
// Fused gather + MFMA transform: out = relu(prelu((A x)_tile @ W^T + b, a)).
// Block = 4 waves = 16 nodes. Gather: half-wave edge pairing; lanes 0-31 and
// 32-63 fetch DIFFERENT edges' rows (8B/lane = 4 bf16): 2 edges per issue
// slot, 8 rows in flight at 4-deep unroll. Rows -> padded LDS tile (+4 pad).
// Then 16x16x32 bf16 MFMA over 8 n-tiles (2 per wave) + bias/prelu/relu.
// Layouts (verified m89/m91): A[m=lane&15][k=quad*8+j], B[n=lane&15][k=...],
// C: col=lane&15, row=quad*4+reg.
// ---------------------------------------------------------------------------
__global__ __launch_bounds__(256) void k_gx(
    const float2* __restrict__ xh2,        // bf16 x rows viewed as float2 (4 bf16)
    const int* __restrict__ off,
    const int2* __restrict__ pair,         // CSR {src, w}
    const unsigned short* __restrict__ wh, // bf16 W [n][k]
    const float* __restrict__ bias, const float* __restrict__ pa,
    float* __restrict__ out)
{
    __shared__ float tile[16][D + 4];

    const int tid = threadIdx.x;
    const int wv = tid >> 6;
    const int lane = tid & 63;
    const int half = lane >> 5;
    const int sl = lane & 31;
    const int m0 = blockIdx.x << 4;
    const float aP = pa[0];

    // ---- gather: 4 nodes per wave, 2 edges per iteration (one per half) ----
    for (int j = 0; j < 4; ++j) {
        const int r = (wv << 2) + j;
        const int n = m0 + r;
        const int beg = off[n], end = off[n + 1];
        float4 acc = make_float4(0.f, 0.f, 0.f, 0.f);

        int e = beg + half;
        for (; e + 6 < end; e += 8) {
            const int2 p0 = pair[e + 0], p1 = pair[e + 2];
            const int2 p2 = pair[e + 4], p3 = pair[e + 6];
            const float2 u0 = xh2[p0.x * 32 + sl];
            const float2 u1 = xh2[p1.x * 32 + sl];
            const float2 u2 = xh2[p2.x * 32 + sl];
            const float2 u3 = xh2[p3.x * 32 + sl];
            const float w0 = __int_as_float(p0.y), w1 = __int_as_float(p1.y);
            const float w2 = __int_as_float(p2.y), w3 = __int_as_float(p3.y);
            const unsigned a0 = __float_as_uint(u0.x), b0 = __float_as_uint(u0.y);
            const unsigned a1 = __float_as_uint(u1.x), b1 = __float_as_uint(u1.y);
            const unsigned a2 = __float_as_uint(u2.x), b2 = __float_as_uint(u2.y);
            const unsigned a3 = __float_as_uint(u3.x), b3 = __float_as_uint(u3.y);
            acc.x += w0 * __uint_as_float(a0 << 16) + w1 * __uint_as_float(a1 << 16)
                   + w2 * __uint_as_float(a2 << 16) + w3 * __uint_as_float(a3 << 16);
            acc.y += w0 * __uint_as_float(a0 & 0xFFFF0000u) + w1 * __uint_as_float(a1 & 0xFFFF0000u)
                   + w2 * __uint_as_float(a2 & 0xFFFF0000u) + w3 * __uint_as_float(a3 & 0xFFFF0000u);
            acc.z += w0 * __uint_as_float(b0 << 16) + w1 * __uint_as_float(b1 << 16)
                   + w2 * __uint_as_float(b2 << 16) + w3 * __uint_as_float(b3 << 16);
            acc.w += w0 * __uint_as_float(b0 & 0xFFFF0000u) + w1 * __uint_as_float(b1 & 0xFFFF0000u)
                   + w2 * __uint_as_float(b2 & 0xFFFF0000u) + w3 * __uint_as_float(b3 & 0xFFFF0000u);
        }
        for (; e < end; e += 2) {
            const int2 p = pair[e];
            const float w = __int_as_float(p.y);
            const float2 u = xh2[p.x * 32 + sl];
            const unsigned a = __float_as_uint(u.x), b = __float_as_uint(u.y);
            acc.x += w * __uint_as_float(a << 16);
            acc.y += w * __uint_as_float(a & 0xFFFF0000u);
            acc.z += w * __uint_as_float(b << 16);
            acc.w += w * __uint_as_float(b & 0xFFFF0000u);
        }
        // fold half 1 into half 0
        acc.x += __shfl_down(acc.x, 32, 64);
        acc.y += __shfl_down(acc.y, 32, 64);
        acc.z += __shfl_down(acc.z, 32, 64);
        acc.w += __shfl_down(acc.w, 32, 64);
        if (half == 0)
            *(float4*)&tile[r][sl * 4] = acc;   // features 4sl..4sl+3
    }
    __syncthreads();

    // ---- MFMA transform on the 16-row tile ----
    const int mm = lane & 15;
    const int quad = lane >> 4;

    bf16x8 af[4];
    #pragma unroll
    for (int c = 0; c < 4; ++c) {
        const float* p = &tile[mm][c * 32 + quad * 8];
        #pragma unroll
        for (int j = 0; j < 8; ++j)
            af[c][j] = bfbits(f2bf(p[j]));
    }

    #pragma unroll
    for (int t = 0; t < 2; ++t) {
        const int n = ((wv * 2 + t) << 4) + mm;
        f32x4 acc = {0.f, 0.f, 0.f, 0.f};
        #pragma unroll
        for (int c = 0; c < 4; ++c) {
            const bf16x8 bf = *(const bf16x8*)(wh + n * D + c * 32 + quad * 8);
            acc = __builtin_amdgcn_mfma_f32_16x16x32_bf16(af[c], bf, acc, 0, 0, 0);
        }
        const float bv = bias[n];
        #pragma unroll
        for (int r = 0; r < 4; ++r) {
            float v = acc[r] + bv;
            v = (v >= 0.f) ? v : aP * v;
            v = fmaxf(v, 0.f);
            out[(size_t)(m0 + (quad << 2) + r) * D + n] = v;
        }
    }
}

// ---------------------------------------------------------------------------
// Tier-C fallbacks (tiny ws): atomic scatter + fp32 vector transform.
// ---------------------------------------------------------------------------
__global__ __launch_bounds__(256) void gcn_scatter(
    const float* __restrict__ x, const int* __restrict__ ei,
    const float* __restrict__ ew, float* __restrict__ agg)
{
    const int lane = threadIdx.x & 63;
    const int wave = (blockIdx.x * blockDim.x + threadIdx.x) >> 6;
    const int nwaves = (gridDim.x * blockDim.x) >> 6;
    for (int e = wave; e < N_EDGES; e += nwaves) {
        const int src = ei[e];
        const int dst = ei[N_EDGES + e];
        const float w = ew[e];
        const float2 v = ((const float2*)(x + (size_t)src * D))[lane];
        float* op = agg + (size_t)dst * D + lane * 2;
        unsafeAtomicAdd(op,     w * v.x);
        unsafeAtomicAdd(op + 1, w * v.y);
    }
}

#define MT 32
__global__ __launch_bounds__(256, 2) void gcn_transform(
    const float* __restrict__ A, const float* __restrict__ W,
    const float* __restrict__ bias, const float* __restrict__ pa,
    float* __restrict__ out)
{
    __shared__ float Wt[D][D];
    __shared__ float xs[MT][D];
    const int tid = threadIdx.x;
    const int row0 = blockIdx.x * MT;

    for (int j = tid; j < D * (D / 4); j += 256) {
        const int n = j & 127;
        const int kg = j >> 7;
        const float4 v = ((const float4*)W)[n * (D / 4) + kg];
        const int k4 = kg << 2;
        Wt[k4 + 0][n] = v.x; Wt[k4 + 1][n] = v.y;
        Wt[k4 + 2][n] = v.z; Wt[k4 + 3][n] = v.w;
    }
    for (int i = tid; i < MT * (D / 4); i += 256) {
        const int r = i >> 5;
        const int c4 = i & 31;
        ((float4*)xs[r])[c4] = ((const float4*)(A + (size_t)(row0 + r) * D))[c4];
    }
    __syncthreads();

    const int tn = tid & 31;
    const int tm = tid >> 5;
    float acc[4][4] = {};
    #pragma unroll
    for (int k = 0; k < D; k += 4) {
        const float4 wv0 = *(const float4*)&Wt[k + 0][tn * 4];
        const float4 wv1 = *(const float4*)&Wt[k + 1][tn * 4];
        const float4 wv2 = *(const float4*)&Wt[k + 2][tn * 4];
        const float4 wv3 = *(const float4*)&Wt[k + 3][tn * 4];
        #pragma unroll
        for (int i = 0; i < 4; ++i) {
            const float4 xv = *(const float4*)&xs[tm * 4 + i][k];
            acc[i][0] += xv.x * wv0.x + xv.y * wv1.x + xv.z * wv2.x + xv.w * wv3.x;
            acc[i][1] += xv.x * wv0.y + xv.y * wv1.y + xv.z * wv2.y + xv.w * wv3.y;
            acc[i][2] += xv.x * wv0.z + xv.y * wv1.z + xv.z * wv2.z + xv.w * wv3.z;
            acc[i][3] += xv.x * wv0.w + xv.y * wv1.w + xv.z * wv2.w + xv.w * wv3.w;
        }
    }
    const float a = pa[0];
    const float4 bv = ((const float4*)bias)[tn];
    #pragma unroll
    for (int i = 0; i < 4; ++i) {
        const int gr = row0 + tm * 4 + i;
        float t0 = acc[i][0] + bv.x, t1 = acc[i][1] + bv.y;
        float t2 = acc[i][2] + bv.z, t3 = acc[i][3] + bv.w;
        float4 r;
        r.x = fmaxf(t0 >= 0.f ? t0 : a * t0, 0.f);
        r.y = fmaxf(t1 >= 0.f ? t1 : a * t1, 0.f);
        r.z = fmaxf(t2 >= 0.f ? t2 : a * t2, 0.f);
        r.w = fmaxf(t3 >= 0.f ? t3 : a * t3, 0.f);
        ((float4*)(out + (size_t)gr * D))[tn] = r;
    }
}

// ---------------------------------------------------------------------------
extern "C" void kernel_launch(void* const* d_in, const int* in_sizes, int n_in,
                              void* d_out, int out_size, void* d_ws, size_t ws_size,
                              hipStream_t stream) {
    const float* x    = (const float*)d_in[0];
    const int*   ei   = (const int*)d_in[1];
    const float* ew   = (const float*)d_in[2];
    const float* W    = (const float*)d_in[3];
    const float* bias = (const float*)d_in[4];
    const float* pa   = (const float*)d_in[5];
    float* out = (float*)d_out;

    // Workspace layout (int units)
    const size_t o_ghist = 0;
    const size_t o_cOff  = o_ghist + NCB;               // 512
    const size_t o_gcur  = o_cOff + NCB + 1;            // 1025
    const size_t o_off   = o_gcur + NCB;                // 1537
    const size_t o_part  = o_off + N_NODES + 1;         // 101538 (8B-aligned)
    const size_t o_wh    = (o_part + 2 * (size_t)N_EDGES + 3) & ~(size_t)3; // 16B-aligned
    const size_t o_xh    = o_wh + (size_t)D * D / 2;    // 16B-aligned
    const size_t endA    = o_xh + (size_t)N_NODES * D / 2;
    const size_t needA   = endA * 4;

    int* wsb = (int*)d_ws;
    int* ghist = wsb + o_ghist;
    int* cOff  = wsb + o_cOff;
    int* gcur  = wsb + o_gcur;
    int* off   = wsb + o_off;
    int2* part = (int2*)(wsb + o_part);
    unsigned short* wh = (unsigned short*)(wsb + o_wh);
    unsigned short* xh = (unsigned short*)(wsb + o_xh);

    if (ws_size >= needA) {
        hipMemsetAsync(ghist, 0, NCB * sizeof(int), stream);
        k_prep <<<XQB + WQB + HB, 256, 0, stream>>>(
            (const float4*)x, (ushort4*)xh, (const float4*)W, (ushort4*)wh, ei, ghist);
        k_cscan<<<1, NCB, 0, stream>>>(ghist, cOff, gcur);
        k_part <<<(N_EDGES + CHUNK - 1) / CHUNK, 256, 0, stream>>>(ei, ew, gcur, part);
        k_csr  <<<NCB, 256, 0, stream>>>(cOff, part, off);
        k_gx   <<<N_NODES / 16, 256, 0, stream>>>(
            (const float2*)xh, off, part, wh, bias, pa, out);
    } else {
        hipMemsetAsync(out, 0, (size_t)N_NODES * D * sizeof(float), stream);
        gcn_scatter<<<12800, 256, 0, stream>>>(x, ei, ew, out);
        gcn_transform<<<N_NODES / MT, 256, 0, stream>>>(out, W, bias, pa, out);
    }
}